// Round 6
// baseline (2238.543 us; speedup 1.0000x reference)
//
#include <hip/hip_runtime.h>

// Decoder_8014408974552 R6: barrier-free streaming design.
// R5 post-mortem: overwriting hold[] per chunk broke GRU semantics
// (gh must use FULL old h; got Gauss-Seidel instead of Jacobi). R4's
// persistent wave-private LDS h (hn) is the correct structure.
// R6 = R4 skeleton with the entire staging machinery deleted:
// all B-frags are plain global_load_dwordx4 from an L2-resident,
// consumption-ordered frag stream. All LDS is wave-private -> ZERO
// __syncthreads, zero vmcnt drains (R4 spent ~60% of cycles there).

#define TT  30
#define HS  392     // hn row stride in u16 (784 B, 16B-aligned, 0 conflicts)

typedef unsigned short u16;
typedef __bf16 bf16x8 __attribute__((ext_vector_type(8)));
typedef u16    u16x8  __attribute__((ext_vector_type(8)));
typedef float  f32x16 __attribute__((ext_vector_type(16)));

__device__ __forceinline__ u16 f2b(float f){           // fp32 -> bf16 RNE
  unsigned u = __float_as_uint(f);
  u += 0x7FFFu + ((u >> 16) & 1u);
  return (u16)(u >> 16);
}
__device__ __forceinline__ float b2f(u16 h){ return __uint_as_float(((unsigned)h) << 16); }

__device__ __forceinline__ f32x16 mfma32(u16x8 a, u16x8 b, f32x16 c){
  return __builtin_amdgcn_mfma_f32_32x32x16_bf16(
      __builtin_bit_cast(bf16x8, a), __builtin_bit_cast(bf16x8, b), c, 0, 0, 0);
}
__device__ __forceinline__ void lds_fence(){ asm volatile("s_waitcnt lgkmcnt(0)" ::: "memory"); }
__device__ __forceinline__ float sigf(float x){ return __builtin_amdgcn_rcpf(1.f + __expf(-x)); }
__device__ __forceinline__ float tanh_(float x){ return 2.f*__builtin_amdgcn_rcpf(1.f + __expf(-2.f*x)) - 1.f; }

// ---------------------------------------------------------------- prep ----
// Single linear frag stream, consumption order (1200 frags x 1024 B):
//   chunk c (0..11), base c*96 frags:
//     [gi_r kf0..7][gi_z kf0..7][gi_n kf0..7]          slots  0..23  (K=128)
//     [gh_r kf0..23]                                   slots 24..47  (K=384)
//     [gh_z kf0..23]                                   slots 48..71
//     [gh_n kf0..23]                                   slots 72..95
//   decode, base 1152 frags: [Wd1 nt0 kf0..23][Wd1 nt1 kf0..23]
// frag: u16 idx (lc + 32*hl)*8 + j -> B[k][n], n = c*32+lc, k = kf*16+hl*8+j
__global__ void prep_kernel(const float* __restrict__ Wih, const float* __restrict__ Whh,
                            const float* __restrict__ Wd1, const float* __restrict__ Wd2,
                            const float* __restrict__ bih, const float* __restrict__ bhh,
                            const float* __restrict__ Ws,  const float* __restrict__ bs,
                            const float* __restrict__ Wp,  const float* __restrict__ bp,
                            u16* __restrict__ sgl, u16* __restrict__ wd2p,
                            u16* __restrict__ wxp, float* __restrict__ gb)
{
  int i = blockIdx.x*blockDim.x + threadIdx.x;
  if (i < 442368){  // W_hh [1152][384] -> gh slots 24 + g*24 + kf
    int row = i/384, k = i - row*384;
    int g = row/384, u = row - g*384, c = u>>5, lc = u&31;
    int kf = k>>4, hl = (k>>3)&1, j = k&7;
    sgl[(size_t)(c*96 + 24 + g*24 + kf)*512 + (lc+32*hl)*8 + j] = f2b(Whh[i]);
  }
  if (i < 147456){  // W_ih [1152][128] -> gi slots g*8 + kf
    int row = i>>7, k = i&127;
    int g = row/384, u = row - g*384, c = u>>5, lc = u&31;
    int kf = k>>4, hl = (k>>3)&1, j = k&7;
    sgl[(size_t)(c*96 + g*8 + kf)*512 + (lc+32*hl)*8 + j] = f2b(Wih[i]);
  }
  if (i < 24576){   // Wd1 [64][384] -> decode base 1152
    int row = i/384, k = i - row*384;
    int nt = row>>5, lc = row&31;
    int kf = k>>4, hl = (k>>3)&1, j = k&7;
    sgl[(size_t)(1152 + nt*24 + kf)*512 + (lc+32*hl)*8 + j] = f2b(Wd1[i]);
  }
  if (i < 2048){    // Wd2 padded B-frags [4 kf][512] (n>=3 -> 0)
    int kf = i>>9, r = i&511;
    int n = (r>>3)&31, hl = r>>8, j = r&7;
    int k = kf*16 + hl*8 + j;
    wd2p[i] = f2b((n<3) ? Wd2[n*64 + k] : 0.f);
  }
  if (i < 2048){    // x-MLP B-frags [4 tiles][512]: K=16 (k=0..7 feat, 8..15 zero)
    int tl = i>>9, r = i&511;
    int n = (r>>3)&31, hl = r>>8, j = r&7;
    int k = hl*8 + j, u = tl*32 + n;
    float v = 0.f;
    if      (k <= 2) v = Ws[u*3 + k];
    else if (k == 3) v = bs[u];
    else if (k <= 6) v = Wp[u*3 + (k-4)];
    else if (k == 7) v = bp[u];
    wxp[i] = f2b(v);
  }
  if (i < 384){     // fused gate biases per hidden unit: {r, z, n_i, n_h}
    gb[i*4+0] = bih[i]       + bhh[i];
    gb[i*4+1] = bih[384+i]   + bhh[384+i];
    gb[i*4+2] = bih[768+i];
    gb[i*4+3] = bhh[768+i];
  }
}

// ---------------------------------------------------------------- main ----
__global__ __launch_bounds__(256, 1)
void gru_main(const float* __restrict__ ih, const float* __restrict__ plan,
              const float* __restrict__ gate, const float* __restrict__ istate,
              const u16* __restrict__ sgl, const u16* __restrict__ wd2p,
              const u16* __restrict__ wxp, const float* __restrict__ gb,
              const float* __restrict__ bd1, const float* __restrict__ bd2,
              float* __restrict__ out)
{
  __shared__ __attribute__((aligned(16))) u16 hn[4][32*HS]; // 100352 B (wave-private h)
  __shared__ float sst[4][32][4];                           //   2048 B

  const int tid  = threadIdx.x;
  const int wave = tid >> 6, lane = tid & 63;
  const int m    = lane & 31, hl = lane >> 5;
  const int R0   = blockIdx.x*128 + wave*32;   // wave's 32 batch rows
  u16* hw = hn[wave];

  const float gt    = gate[R0 + m];
  const float bd1v0 = bd1[m], bd1v1 = bd1[32+m];
  const float bd2v  = (m<3) ? bd2[m] : 0.f;

  if (lane < 32){
    const float* sp = istate + (size_t)(R0+lane)*3;
    sst[wave][lane][0]=sp[0]; sst[wave][lane][1]=sp[1];
    sst[wave][lane][2]=sp[2]; sst[wave][lane][3]=0.f;
  }

  // initial hidden -> A-frags AND the persistent LDS h-buffer
  u16x8 hold[24];
#pragma unroll
  for (int kf=0; kf<24; ++kf){
    const float* p = ih + (size_t)(R0+m)*384 + kf*16 + hl*8;
    float4 a = *(const float4*)p;
    float4 b = *(const float4*)(p+4);
    u16x8 v;
    v[0]=f2b(a.x); v[1]=f2b(a.y); v[2]=f2b(a.z); v[3]=f2b(a.w);
    v[4]=f2b(b.x); v[5]=f2b(b.y); v[6]=f2b(b.z); v[7]=f2b(b.w);
    hold[kf]=v;
    *(u16x8*)&hw[m*HS + kf*16 + hl*8] = v;
  }
  lds_fence();

#pragma unroll 1
  for (int t=0; t<TT; ++t){
    // ---- x = (state@Ws^T+bs) + gate*(plan@Wp^T+bp) via padded-K MFMA
    u16x8 a8;
    {
      float4 sv = *(const float4*)&sst[wave][m][0];
      const float* pp = plan + (size_t)(R0+m)*(TT*3) + t*3;
      float f0=sv.x, f1=sv.y, f2=sv.z, f3=1.f;
      float f4=gt*pp[0], f5=gt*pp[1], f6=gt*pp[2], f7=gt;
      if (hl){ a8[0]=0;a8[1]=0;a8[2]=0;a8[3]=0;a8[4]=0;a8[5]=0;a8[6]=0;a8[7]=0; }
      else { a8[0]=f2b(f0);a8[1]=f2b(f1);a8[2]=f2b(f2);a8[3]=f2b(f3);
             a8[4]=f2b(f4);a8[5]=f2b(f5);a8[6]=f2b(f6);a8[7]=f2b(f7); }
    }
    u16x8 xf[8];
#pragma unroll
    for (int tl=0; tl<4; ++tl){
      f32x16 ax;
#pragma unroll
      for (int r=0;r<16;++r) ax[r]=0.f;
      ax = mfma32(a8, *(const u16x8*)(wxp + tl*512 + lane*8), ax);
      // C-layout -> hn chunk-0 slice (scratch) -> A-frags
#pragma unroll
      for (int r=0;r<16;++r){
        int row = (r&3) + ((r>>2)<<3) + 4*hl;
        hw[row*HS + m] = f2b(ax[r]);
      }
      lds_fence();
      xf[2*tl]   = *(const u16x8*)&hw[m*HS + hl*8];
      xf[2*tl+1] = *(const u16x8*)&hw[m*HS + 16 + hl*8];
      lds_fence();
    }
    // restore chunk-0 slice of old h from hold (CONSTANT indices)
    *(u16x8*)&hw[m*HS + hl*8]      = hold[0];
    *(u16x8*)&hw[m*HS + 16 + hl*8] = hold[1];
    lds_fence();

    // ---- 12 unit-chunks, no barriers: B-frags straight from L2
#pragma unroll 1
    for (int c=0; c<12; ++c){
      const u16* gB = sgl + (size_t)c*96*512 + lane*8;

      f32x16 aR, aZ, aNI, aNH;
      {
        const float4 b4 = *(const float4*)(gb + (size_t)(c*32+m)*4);
#pragma unroll
        for (int r=0;r<16;++r){ aR[r]=b4.x; aZ[r]=b4.y; aNI[r]=b4.z; aNH[r]=b4.w; }
      }
      // gi: K=128 (slots 0..23)
#pragma unroll
      for (int kf=0; kf<8; ++kf){
        u16x8 bR = *(const u16x8*)(gB + (     kf)*512);
        u16x8 bZ = *(const u16x8*)(gB + ( 8 + kf)*512);
        u16x8 bN = *(const u16x8*)(gB + (16 + kf)*512);
        aR  = mfma32(xf[kf], bR, aR);
        aZ  = mfma32(xf[kf], bZ, aZ);
        aNI = mfma32(xf[kf], bN, aNI);
      }
      // gh: K=384 from FULL old h (hold regs, untouched all step)
#pragma unroll
      for (int kf=0; kf<24; ++kf){
        u16x8 bR = *(const u16x8*)(gB + (24 + kf)*512);
        u16x8 bZ = *(const u16x8*)(gB + (48 + kf)*512);
        u16x8 bN = *(const u16x8*)(gB + (72 + kf)*512);
        aR  = mfma32(hold[kf], bR, aR);
        aZ  = mfma32(hold[kf], bZ, aZ);
        aNH = mfma32(hold[kf], bN, aNH);
      }
      // GRU elementwise, blended in place in hn chunk slice (old h lives there)
#pragma unroll
      for (int r=0;r<16;++r){
        int row = (r&3) + ((r>>2)<<3) + 4*hl;
        float rr = sigf(aR[r]);
        float zz = sigf(aZ[r]);
        float nn = tanh_(aNI[r] + rr*aNH[r]);
        int off = row*HS + c*32 + m;
        float ho = b2f(hw[off]);             // old h
        hw[off] = f2b((1.f-zz)*nn + zz*ho);  // new h, in place
      }
    } // chunks

    // ---- reload hold[] from hn (full new h for this wave's 32 rows)
    lds_fence();
#pragma unroll
    for (int kf=0; kf<24; ++kf)
      hold[kf] = *(const u16x8*)&hw[m*HS + kf*16 + hl*8];

    // ---- decode: d1 = elu(h@Wd1^T + bd1) [2 tiles], then d2 via padded-N MFMA
    {
      const u16* dB = sgl + (size_t)1152*512 + lane*8;
      f32x16 a0, a1;
#pragma unroll
      for (int r=0;r<16;++r){ a0[r]=bd1v0; a1[r]=bd1v1; }
#pragma unroll
      for (int kf=0; kf<24; ++kf){
        u16x8 b0 = *(const u16x8*)(dB + (     kf)*512);
        a0 = mfma32(hold[kf], b0, a0);
        u16x8 b1 = *(const u16x8*)(dB + (24 + kf)*512);
        a1 = mfma32(hold[kf], b1, a1);
      }
      u16x8 wd2f0 = *(const u16x8*)(wd2p + 0*512 + lane*8);
      u16x8 wd2f1 = *(const u16x8*)(wd2p + 1*512 + lane*8);
      u16x8 wd2f2 = *(const u16x8*)(wd2p + 2*512 + lane*8);
      u16x8 wd2f3 = *(const u16x8*)(wd2p + 3*512 + lane*8);

      f32x16 ao;
#pragma unroll
      for (int r=0;r<16;++r) ao[r]=0.f;
      // pass 0: d1 units 0..31 (hn chunk-0 slice as scratch)
#pragma unroll
      for (int r=0;r<16;++r){
        int row = (r&3) + ((r>>2)<<3) + 4*hl;
        float e = a0[r]; e = e>0.f ? e : (__expf(e)-1.f);
        hw[row*HS + m] = f2b(e);
      }
      lds_fence();
      {
        u16x8 af0 = *(const u16x8*)&hw[m*HS + hl*8];
        u16x8 af1 = *(const u16x8*)&hw[m*HS + 16 + hl*8];
        ao = mfma32(af0, wd2f0, ao);
        ao = mfma32(af1, wd2f1, ao);
      }
      lds_fence();
      // pass 1: d1 units 32..63
#pragma unroll
      for (int r=0;r<16;++r){
        int row = (r&3) + ((r>>2)<<3) + 4*hl;
        float e = a1[r]; e = e>0.f ? e : (__expf(e)-1.f);
        hw[row*HS + m] = f2b(e);
      }
      lds_fence();
      {
        u16x8 af0 = *(const u16x8*)&hw[m*HS + hl*8];
        u16x8 af1 = *(const u16x8*)&hw[m*HS + 16 + hl*8];
        ao = mfma32(af0, wd2f2, ao);
        ao = mfma32(af1, wd2f3, ao);
      }
      lds_fence();
      // restore chunk-0 slice of NEW h from hold (CONSTANT indices)
      *(u16x8*)&hw[m*HS + hl*8]      = hold[0];
      *(u16x8*)&hw[m*HS + 16 + hl*8] = hold[1];

      // out + state update (C cols 0..2 valid)
#pragma unroll
      for (int r=0;r<16;++r){
        int row = (r&3) + ((r>>2)<<3) + 4*hl;
        if (m < 3){
          float ns = sst[wave][row][m] + ao[r] + bd2v;
          out[(size_t)(R0+row)*(TT*3) + t*3 + m] = ns;
          sst[wave][row][m] = ns;
        }
      }
      lds_fence();
    }
  } // t
}

// -------------------------------------------------------------- launch ----
extern "C" void kernel_launch(void* const* d_in, const int* in_sizes, int n_in,
                              void* d_out, int out_size, void* d_ws, size_t ws_size,
                              hipStream_t stream)
{
  (void)in_sizes; (void)n_in; (void)out_size; (void)ws_size;
  const float* ih     = (const float*)d_in[0];
  const float* plan   = (const float*)d_in[1];
  const float* gatep  = (const float*)d_in[2];
  const float* istate = (const float*)d_in[3];
  const float* Wp     = (const float*)d_in[4];
  const float* bp     = (const float*)d_in[5];
  const float* Ws     = (const float*)d_in[6];
  const float* bs     = (const float*)d_in[7];
  const float* Wih    = (const float*)d_in[8];
  const float* bih    = (const float*)d_in[9];
  const float* Whh    = (const float*)d_in[10];
  const float* bhh    = (const float*)d_in[11];
  const float* Wd1    = (const float*)d_in[12];
  const float* bd1    = (const float*)d_in[13];
  const float* Wd2    = (const float*)d_in[14];
  const float* bd2    = (const float*)d_in[15];

  // workspace layout (~1.24 MB)
  u16*   sgl  = (u16*)d_ws;                            // 1200*512 u16 = 1228800 B
  u16*   wd2p = (u16*)((char*)d_ws + 1228800);         //   2048 u16  =    4096 B
  u16*   wxp  = (u16*)((char*)d_ws + 1232896);         //   2048 u16  =    4096 B
  float* gb   = (float*)((char*)d_ws + 1236992);       //   1536 f32  =    6144 B

  prep_kernel<<<1728, 256, 0, stream>>>(Wih, Whh, Wd1, Wd2, bih, bhh, Ws, bs, Wp, bp,
                                        sgl, wd2p, wxp, gb);
  gru_main<<<256, 256, 0, stream>>>(ih, plan, gatep, istate,
                                    sgl, wd2p, wxp, gb, bd1, bd2, (float*)d_out);
}

// Round 7
// 2147.990 us; speedup vs baseline: 1.0422x; 1.0422x over previous
//
#include <hip/hip_runtime.h>

// Decoder_8014408974552 R7: cooperative triple-buffered weight staging with
// non-draining barriers (AITER pattern). R6 post-mortem: per-wave global
// streaming is L2-BW-bound (4x redundant, ~37GB L2/launch). R4 post-mortem:
// cooperative staging pays 50 full vmcnt(0) drains/step (~60% of cycles).
// R7: 16KB phases, 3 LDS buffers; consume phase p while p+1 is landed and
// p+2 in flight; pre-barrier wait = s_waitcnt vmcnt(4) (confirms loads from
// TWO phases ago) + raw s_barrier -- the load pipe never drains.
// h-state: R6's verified skeleton (wave-private hn, in-place Jacobi blend).

#define TT  30
#define HS  392       // hn row stride in u16 (784 B, 16B-aligned)
#define PHU 8192      // u16 per phase (16 KB = 16 frags x 512)

typedef unsigned short u16;
typedef __bf16 bf16x8 __attribute__((ext_vector_type(8)));
typedef u16    u16x8  __attribute__((ext_vector_type(8)));
typedef float  f32x16 __attribute__((ext_vector_type(16)));

__device__ __forceinline__ u16 f2b(float f){           // fp32 -> bf16 RNE
  unsigned u = __float_as_uint(f);
  u += 0x7FFFu + ((u >> 16) & 1u);
  return (u16)(u >> 16);
}
__device__ __forceinline__ float b2f(u16 h){ return __uint_as_float(((unsigned)h) << 16); }

__device__ __forceinline__ f32x16 mfma32(u16x8 a, u16x8 b, f32x16 c){
  return __builtin_amdgcn_mfma_f32_32x32x16_bf16(
      __builtin_bit_cast(bf16x8, a), __builtin_bit_cast(bf16x8, b), c, 0, 0, 0);
}
__device__ __forceinline__ void lds_fence(){ asm volatile("s_waitcnt lgkmcnt(0)" ::: "memory"); }
// Non-draining phase barrier: oldest in-flight stage batch (4 loads, issued
// two phases ago) must have landed; newest batch (4) stays in flight.
__device__ __forceinline__ void waitb(){
  asm volatile("s_waitcnt vmcnt(4) lgkmcnt(0)\n\ts_barrier" ::: "memory");
}
__device__ __forceinline__ float sigf(float x){ return __builtin_amdgcn_rcpf(1.f + __expf(-x)); }
__device__ __forceinline__ float tanh_(float x){ return 2.f*__builtin_amdgcn_rcpf(1.f + __expf(-2.f*x)) - 1.f; }

__device__ __forceinline__ void stage16(const u16* g, u16* l){
  __builtin_amdgcn_global_load_lds(
      (const __attribute__((address_space(1))) unsigned int*)g,
      (__attribute__((address_space(3))) unsigned int*)l, 16, 0, 0);
}

// ---------------------------------------------------------------- prep ----
// Linear frag stream, consumption order (1200 frags x 1024 B), same as R6:
//   chunk c (0..11), base c*96: [gi_r kf0..7][gi_z][gi_n] [gh_r kf0..23]
//                               [gh_z kf0..23][gh_n kf0..23]
//   decode base 1152: [Wd1 nt0 kf0..23][Wd1 nt1 kf0..23]
// Phase p = frags 16p..16p+15 (75 phases/step).
__global__ void prep_kernel(const float* __restrict__ Wih, const float* __restrict__ Whh,
                            const float* __restrict__ Wd1, const float* __restrict__ Wd2,
                            const float* __restrict__ bih, const float* __restrict__ bhh,
                            const float* __restrict__ Ws,  const float* __restrict__ bs,
                            const float* __restrict__ Wp,  const float* __restrict__ bp,
                            u16* __restrict__ sgl, u16* __restrict__ wd2p,
                            u16* __restrict__ wxp, float* __restrict__ gb)
{
  int i = blockIdx.x*blockDim.x + threadIdx.x;
  if (i < 442368){  // W_hh [1152][384] -> gh slots 24 + g*24 + kf
    int row = i/384, k = i - row*384;
    int g = row/384, u = row - g*384, c = u>>5, lc = u&31;
    int kf = k>>4, hl = (k>>3)&1, j = k&7;
    sgl[(size_t)(c*96 + 24 + g*24 + kf)*512 + (lc+32*hl)*8 + j] = f2b(Whh[i]);
  }
  if (i < 147456){  // W_ih [1152][128] -> gi slots g*8 + kf
    int row = i>>7, k = i&127;
    int g = row/384, u = row - g*384, c = u>>5, lc = u&31;
    int kf = k>>4, hl = (k>>3)&1, j = k&7;
    sgl[(size_t)(c*96 + g*8 + kf)*512 + (lc+32*hl)*8 + j] = f2b(Wih[i]);
  }
  if (i < 24576){   // Wd1 [64][384] -> decode base 1152
    int row = i/384, k = i - row*384;
    int nt = row>>5, lc = row&31;
    int kf = k>>4, hl = (k>>3)&1, j = k&7;
    sgl[(size_t)(1152 + nt*24 + kf)*512 + (lc+32*hl)*8 + j] = f2b(Wd1[i]);
  }
  if (i < 2048){    // Wd2 padded B-frags [4 kf][512] (n>=3 -> 0)
    int kf = i>>9, r = i&511;
    int n = (r>>3)&31, hl = r>>8, j = r&7;
    int k = kf*16 + hl*8 + j;
    wd2p[i] = f2b((n<3) ? Wd2[n*64 + k] : 0.f);
  }
  if (i < 2048){    // x-MLP B-frags [4 tiles][512]: K=16 (k=0..7 feat, 8..15 zero)
    int tl = i>>9, r = i&511;
    int n = (r>>3)&31, hl = r>>8, j = r&7;
    int k = hl*8 + j, u = tl*32 + n;
    float v = 0.f;
    if      (k <= 2) v = Ws[u*3 + k];
    else if (k == 3) v = bs[u];
    else if (k <= 6) v = Wp[u*3 + (k-4)];
    else if (k == 7) v = bp[u];
    wxp[i] = f2b(v);
  }
  if (i < 384){     // fused gate biases per hidden unit: {r, z, n_i, n_h}
    gb[i*4+0] = bih[i]       + bhh[i];
    gb[i*4+1] = bih[384+i]   + bhh[384+i];
    gb[i*4+2] = bih[768+i];
    gb[i*4+3] = bhh[768+i];
  }
}

// ---------------------------------------------------------------- main ----
__global__ __launch_bounds__(256, 1)
void gru_main(const float* __restrict__ ih, const float* __restrict__ plan,
              const float* __restrict__ gate, const float* __restrict__ istate,
              const u16* __restrict__ sgl, const u16* __restrict__ wd2p,
              const u16* __restrict__ wxp, const float* __restrict__ gb,
              const float* __restrict__ bd1, const float* __restrict__ bd2,
              float* __restrict__ out)
{
  __shared__ __attribute__((aligned(16))) u16 wbs[3][PHU];  //  49152 B
  __shared__ __attribute__((aligned(16))) u16 hn[4][32*HS]; // 100352 B
  __shared__ float gbl[1536];                               //   6144 B
  __shared__ float sst[4][32][4];                           //   2048 B

  const int tid  = threadIdx.x;
  const int wave = tid >> 6, lane = tid & 63;
  const int m    = lane & 31, hl = lane >> 5;
  const int R0   = blockIdx.x*128 + wave*32;   // wave's 32 batch rows
  u16* hw = hn[wave];

  const float gt    = gate[R0 + m];
  const float bd1v0 = bd1[m], bd1v1 = bd1[32+m];
  const float bd2v  = (m<3) ? bd2[m] : 0.f;

  // t-invariant frag preloads (keep chunk loop free of extra VMEM)
  u16x8 wxpf[4], wd2f[4];
#pragma unroll
  for (int tl=0; tl<4; ++tl){
    wxpf[tl] = *(const u16x8*)(wxp  + tl*512 + lane*8);
    wd2f[tl] = *(const u16x8*)(wd2p + tl*512 + lane*8);
  }
  for (int i = tid; i < 1536; i += 256) gbl[i] = gb[i];   // biases -> LDS

  if (lane < 32){
    const float* sp = istate + (size_t)(R0+lane)*3;
    sst[wave][lane][0]=sp[0]; sst[wave][lane][1]=sp[1];
    sst[wave][lane][2]=sp[2]; sst[wave][lane][3]=0.f;
  }

  // initial hidden -> A-frags AND the persistent LDS h-buffer
  u16x8 hold[24];
#pragma unroll
  for (int kf=0; kf<24; ++kf){
    const float* p = ih + (size_t)(R0+m)*384 + kf*16 + hl*8;
    float4 a = *(const float4*)p;
    float4 b = *(const float4*)(p+4);
    u16x8 v;
    v[0]=f2b(a.x); v[1]=f2b(a.y); v[2]=f2b(a.z); v[3]=f2b(a.w);
    v[4]=f2b(b.x); v[5]=f2b(b.y); v[6]=f2b(b.z); v[7]=f2b(b.w);
    hold[kf]=v;
    *(u16x8*)&hw[m*HS + kf*16 + hl*8] = v;
  }

  // wave stages 4 frags of global phase q into buffer dst
  auto stageb = [&](int q, u16* dst){
    const u16* s = sgl + (size_t)q*PHU + (wave*4)*512 + lane*8;
    u16* d = dst + (wave*4)*512 + lane*8;
    stage16(s+0*512, d+0*512); stage16(s+1*512, d+1*512);
    stage16(s+2*512, d+2*512); stage16(s+3*512, d+3*512);
  };

  asm volatile("s_waitcnt vmcnt(0) lgkmcnt(0)" ::: "memory");
  __syncthreads();                       // init published (gbl, sst)
  stageb(0, wbs[0]);
  stageb(1, wbs[1]);
  waitb();                               // phase 0 ready; phase 1 in flight

#pragma unroll 1
  for (int t=0; t<TT; ++t){
    // ---- x = (state@Ws^T+bs) + gate*(plan@Wp^T+bp) via padded-K MFMA
    u16x8 a8;
    {
      float4 sv = *(const float4*)&sst[wave][m][0];
      const float* pp = plan + (size_t)(R0+m)*(TT*3) + t*3;
      float f0=sv.x, f1=sv.y, f2=sv.z, f3=1.f;
      float f4=gt*pp[0], f5=gt*pp[1], f6=gt*pp[2], f7=gt;  // drains once/step
      if (hl){ a8[0]=0;a8[1]=0;a8[2]=0;a8[3]=0;a8[4]=0;a8[5]=0;a8[6]=0;a8[7]=0; }
      else { a8[0]=f2b(f0);a8[1]=f2b(f1);a8[2]=f2b(f2);a8[3]=f2b(f3);
             a8[4]=f2b(f4);a8[5]=f2b(f5);a8[6]=f2b(f6);a8[7]=f2b(f7); }
    }
    u16x8 xf[8];
#pragma unroll
    for (int tl=0; tl<4; ++tl){
      f32x16 ax;
#pragma unroll
      for (int r=0;r<16;++r) ax[r]=0.f;
      ax = mfma32(a8, wxpf[tl], ax);
#pragma unroll
      for (int r=0;r<16;++r){
        int row = (r&3) + ((r>>2)<<3) + 4*hl;
        hw[row*HS + m] = f2b(ax[r]);
      }
      lds_fence();
      xf[2*tl]   = *(const u16x8*)&hw[m*HS + hl*8];
      xf[2*tl+1] = *(const u16x8*)&hw[m*HS + 16 + hl*8];
      lds_fence();
    }
    // restore chunk-0 slice of old h (CONSTANT indices)
    *(u16x8*)&hw[m*HS + hl*8]      = hold[0];
    *(u16x8*)&hw[m*HS + 16 + hl*8] = hold[1];
    lds_fence();

    // ---- 12 unit-chunks x 6 phases; consume buf[p%3], stage p+2
#pragma unroll 1
    for (int c=0; c<12; ++c){
      f32x16 aR, aZ, aNI, aNH;
      {
        const float4 b4 = *(const float4*)&gbl[(c*32+m)*4];
#pragma unroll
        for (int r=0;r<16;++r){ aR[r]=b4.x; aZ[r]=b4.y; aNI[r]=b4.z; aNH[r]=b4.w; }
      }
#pragma unroll
      for (int s=0; s<6; ++s){
        stageb(6*c + s + 2, wbs[(s+2)%3]);     // 6c%3==0: buffers align per chunk
        const u16* W = wbs[s%3];
#pragma unroll
        for (int ff=0; ff<16; ++ff){
          const int f = s*16 + ff;
          u16x8 b = *(const u16x8*)(W + ff*512 + lane*8);
          if      (f <  8) aR  = mfma32(xf[f],        b, aR);
          else if (f < 16) aZ  = mfma32(xf[f-8],      b, aZ);
          else if (f < 24) aNI = mfma32(xf[f-16],     b, aNI);
          else if (f < 48) aR  = mfma32(hold[f-24],   b, aR);
          else if (f < 72) aZ  = mfma32(hold[f-48],   b, aZ);
          else             aNH = mfma32(hold[f-72],   b, aNH);
        }
        waitb();
      }
      // GRU elementwise, in place in hn chunk slice (old h lives there)
#pragma unroll
      for (int r=0;r<16;++r){
        int row = (r&3) + ((r>>2)<<3) + 4*hl;
        float rr = sigf(aR[r]);
        float zz = sigf(aZ[r]);
        float nn = tanh_(aNI[r] + rr*aNH[r]);
        int off = row*HS + c*32 + m;
        float ho = b2f(hw[off]);
        hw[off] = f2b((1.f-zz)*nn + zz*ho);
      }
    } // chunks

    // ---- reload hold[] from hn (full new h)
    lds_fence();
#pragma unroll
    for (int kf=0; kf<24; ++kf)
      hold[kf] = *(const u16x8*)&hw[m*HS + kf*16 + hl*8];

    // ---- decode: phases 72..74 (Wd1), then wd2 epilogue inside s2=2
    f32x16 a0, a1;
#pragma unroll
    for (int r=0;r<16;++r){ a0[r]=bd1v0; a1[r]=bd1v1; }
#pragma unroll
    for (int s2=0; s2<3; ++s2){
      const int q2  = (s2==0) ? 74 : (s2-1);        // (74+s2) mod 75
      const int bst = (74+s2)%3;                    // stage target buffer
      stageb(q2, wbs[bst]);
      const u16* W = wbs[s2];                       // (72+s2)%3 == s2
#pragma unroll
      for (int ff=0; ff<16; ++ff){
        const int d = s2*16 + ff;
        u16x8 b = *(const u16x8*)(W + ff*512 + lane*8);
        if (d < 24) a0 = mfma32(hold[d],    b, a0);
        else        a1 = mfma32(hold[d-24], b, a1);
      }
      if (s2 < 2){ waitb(); continue; }

      // ---- epilogue (inside last decode phase, before its barrier)
      f32x16 ao;
#pragma unroll
      for (int r=0;r<16;++r) ao[r]=0.f;
#pragma unroll
      for (int r=0;r<16;++r){
        int row = (r&3) + ((r>>2)<<3) + 4*hl;
        float e = a0[r]; e = e>0.f ? e : (__expf(e)-1.f);
        hw[row*HS + m] = f2b(e);
      }
      lds_fence();
      {
        u16x8 af0 = *(const u16x8*)&hw[m*HS + hl*8];
        u16x8 af1 = *(const u16x8*)&hw[m*HS + 16 + hl*8];
        ao = mfma32(af0, wd2f[0], ao);
        ao = mfma32(af1, wd2f[1], ao);
      }
      lds_fence();
#pragma unroll
      for (int r=0;r<16;++r){
        int row = (r&3) + ((r>>2)<<3) + 4*hl;
        float e = a1[r]; e = e>0.f ? e : (__expf(e)-1.f);
        hw[row*HS + m] = f2b(e);
      }
      lds_fence();
      {
        u16x8 af0 = *(const u16x8*)&hw[m*HS + hl*8];
        u16x8 af1 = *(const u16x8*)&hw[m*HS + 16 + hl*8];
        ao = mfma32(af0, wd2f[2], ao);
        ao = mfma32(af1, wd2f[3], ao);
      }
      lds_fence();
      // restore chunk-0 slice of NEW h (CONSTANT indices)
      *(u16x8*)&hw[m*HS + hl*8]      = hold[0];
      *(u16x8*)&hw[m*HS + 16 + hl*8] = hold[1];

      // out + state update (C cols 0..2 valid); stores drain at next waitb
#pragma unroll
      for (int r=0;r<16;++r){
        int row = (r&3) + ((r>>2)<<3) + 4*hl;
        if (m < 3){
          float ns = sst[wave][row][m] + ao[r] + bd2v;
          out[(size_t)(R0+row)*(TT*3) + t*3 + m] = ns;
          sst[wave][row][m] = ns;
        }
      }
      waitb();   // publishes next step's phase 0
    }
  } // t
}

// -------------------------------------------------------------- launch ----
extern "C" void kernel_launch(void* const* d_in, const int* in_sizes, int n_in,
                              void* d_out, int out_size, void* d_ws, size_t ws_size,
                              hipStream_t stream)
{
  (void)in_sizes; (void)n_in; (void)out_size; (void)ws_size;
  const float* ih     = (const float*)d_in[0];
  const float* plan   = (const float*)d_in[1];
  const float* gatep  = (const float*)d_in[2];
  const float* istate = (const float*)d_in[3];
  const float* Wp     = (const float*)d_in[4];
  const float* bp     = (const float*)d_in[5];
  const float* Ws     = (const float*)d_in[6];
  const float* bs     = (const float*)d_in[7];
  const float* Wih    = (const float*)d_in[8];
  const float* bih    = (const float*)d_in[9];
  const float* Whh    = (const float*)d_in[10];
  const float* bhh    = (const float*)d_in[11];
  const float* Wd1    = (const float*)d_in[12];
  const float* bd1    = (const float*)d_in[13];
  const float* Wd2    = (const float*)d_in[14];
  const float* bd2    = (const float*)d_in[15];

  // workspace layout (~1.24 MB)
  u16*   sgl  = (u16*)d_ws;                            // 1200*512 u16 = 1228800 B
  u16*   wd2p = (u16*)((char*)d_ws + 1228800);         //   2048 u16  =    4096 B
  u16*   wxp  = (u16*)((char*)d_ws + 1232896);         //   2048 u16  =    4096 B
  float* gb   = (float*)((char*)d_ws + 1236992);       //   1536 f32  =    6144 B

  prep_kernel<<<1728, 256, 0, stream>>>(Wih, Whh, Wd1, Wd2, bih, bhh, Ws, bs, Wp, bp,
                                        sgl, wd2p, wxp, gb);
  gru_main<<<256, 256, 0, stream>>>(ih, plan, gatep, istate,
                                    sgl, wd2p, wxp, gb, bd1, bd2, (float*)d_out);
}